// Round 8
// baseline (292.090 us; speedup 1.0000x reference)
//
#include <hip/hip_runtime.h>
#include <math.h>

#define T 2048
#define HIDDEN 2048
#define NH 16
#define NKV 4
#define HD 128
#define QKV_N 3072   // (16 + 2*4) * 128
#define Q_SIZE 2048  // 16*128
#define KV_SIZE 512  // 4*128

typedef __attribute__((ext_vector_type(8))) short short8;
typedef __attribute__((ext_vector_type(4))) short short4v;
typedef __attribute__((ext_vector_type(4))) float floatx4;
typedef __attribute__((ext_vector_type(16))) float floatx16;

// counted-waitcnt plumbing: memory-clobber asm fences prevent the compiler from
// moving loads/gload_lds across the wait+barrier pair
#define VMCNT(N) asm volatile("s_waitcnt vmcnt(" #N ")" ::: "memory")
#define LGKMCNT0 asm volatile("s_waitcnt lgkmcnt(0)" ::: "memory")
#define BARRIER_RAW()                          \
    do {                                       \
        __builtin_amdgcn_s_barrier();          \
        asm volatile("" ::: "memory");         \
    } while (0)

__device__ __forceinline__ unsigned short f2bf(float f) {
    union { float f; unsigned int u; } v; v.f = f;
    unsigned int u = v.u;
    u += 0x7fffu + ((u >> 16) & 1u);   // round-to-nearest-even
    return (unsigned short)(u >> 16);
}

// async global->LDS, 16B per lane; LDS dest = wave-uniform base + lane*16 (HW adds it)
__device__ __forceinline__ void gload_lds16(const unsigned short* g, unsigned short* l) {
    __builtin_amdgcn_global_load_lds((const __attribute__((address_space(1))) unsigned int*)g,
                                     (__attribute__((address_space(3))) unsigned int*)l, 16, 0, 0);
}

// ---------------- fused prep: convert hb + transpose wqt + transpose wot + cos/sin ----------------
__global__ __launch_bounds__(256) void prep_misc(const float* __restrict__ hidden,
                                                 const float* __restrict__ w_qkv,
                                                 const float* __restrict__ w_o,
                                                 const int* __restrict__ positions,
                                                 unsigned short* __restrict__ hb,
                                                 unsigned short* __restrict__ wqt,
                                                 unsigned short* __restrict__ wot,
                                                 float* __restrict__ cosT,
                                                 float* __restrict__ sinT) {
    __shared__ float tile[32][33];
    const int b = blockIdx.x;
    const int tid = threadIdx.x;
    const int tx = tid & 31, ty = tid >> 5;

    if (b < 4096) {
        int i = (b * 256 + tid) * 4;
        float4 v = *(const float4*)(hidden + i);
        hb[i]     = f2bf(v.x);
        hb[i + 1] = f2bf(v.y);
        hb[i + 2] = f2bf(v.z);
        hb[i + 3] = f2bf(v.w);
    } else if (b < 10240) {
        int idx = b - 4096;
        int c0 = (idx % 96) * 32, r0 = (idx / 96) * 32;
#pragma unroll
        for (int i = 0; i < 4; ++i)
            tile[ty + i * 8][tx] = w_qkv[(long)(r0 + ty + i * 8) * QKV_N + c0 + tx];
        __syncthreads();
#pragma unroll
        for (int i = 0; i < 4; ++i)
            wqt[(long)(c0 + ty + i * 8) * HIDDEN + r0 + tx] = f2bf(tile[tx][ty + i * 8]);
    } else if (b < 14336) {
        int idx = b - 10240;
        int c0 = (idx % 64) * 32, r0 = (idx / 64) * 32;
#pragma unroll
        for (int i = 0; i < 4; ++i)
            tile[ty + i * 8][tx] = w_o[(long)(r0 + ty + i * 8) * HIDDEN + c0 + tx];
        __syncthreads();
#pragma unroll
        for (int i = 0; i < 4; ++i)
            wot[(long)(c0 + ty + i * 8) * HIDDEN + r0 + tx] = f2bf(tile[tx][ty + i * 8]);
    } else {
        int idx = b - 14336;
        int t = idx * 4 + (tid >> 6);
        int j = tid & 63;
        int row = (j >= 44) ? 0 : ((j & 1) ? 2 : 1);
        int pos = positions[row * T + t];
        float invf = exp2f((float)j * -0.29580571f);   // log2(500000)/64
        float ang = (float)pos * invf;
        cosT[t * 64 + j] = cosf(ang);
        sinT[t * 64 + j] = sinf(ang);
    }
}

// ---------------- qkv GEMM (v0, measured 45.4us): 64x128 tile, BK=64, dbuf async, rope fused ----
// also zeroes the fa split-k flags (runs before fa; kernel boundary flushes L2 -> visible)
__global__ __launch_bounds__(256) void gemm_qkv(const unsigned short* __restrict__ A,
                                                const unsigned short* __restrict__ B,
                                                const float* __restrict__ cosT,
                                                const float* __restrict__ sinT,
                                                unsigned short* __restrict__ qb,
                                                unsigned short* __restrict__ kb,
                                                unsigned short* __restrict__ vt,
                                                int* __restrict__ flags) {
    __shared__ __align__(16) unsigned short As[2][64 * 64];    // 2 x 8 KB
    __shared__ __align__(16) unsigned short Bs[2][128 * 64];   // 2 x 16 KB
    const int K = HIDDEN;
    const int tid = threadIdx.x;
    const int wv = tid >> 6;
    const int lane = tid & 63;
    const int m = lane & 15, qd = lane >> 4;
    const unsigned short* Ab = A + (long)(blockIdx.x * 64) * K;
    const unsigned short* Bb = B + (long)(blockIdx.y * 128) * K;

    if (blockIdx.x == 0 && blockIdx.y == 0) flags[tid] = 0;   // 256 flags

    floatx4 acc[4][2];
#pragma unroll
    for (int i = 0; i < 4; ++i)
#pragma unroll
        for (int j = 0; j < 2; ++j) acc[i][j] = (floatx4){0.f, 0.f, 0.f, 0.f};

#define QKV_STAGE(buf, k0)                                                                   \
    do {                                                                                     \
        _Pragma("unroll") for (int i_ = 0; i_ < 2; ++i_) {                                   \
            int s_ = i_ * 256 + tid, r_ = s_ >> 3, c_ = (s_ & 7) ^ (r_ & 7);                 \
            gload_lds16(Ab + (long)r_ * K + (k0) + c_ * 8, &As[buf][i_ * 2048 + wv * 512]);  \
        }                                                                                    \
        _Pragma("unroll") for (int i_ = 0; i_ < 4; ++i_) {                                   \
            int s_ = i_ * 256 + tid, r_ = s_ >> 3, c_ = (s_ & 7) ^ (r_ & 7);                 \
            gload_lds16(Bb + (long)r_ * K + (k0) + c_ * 8, &Bs[buf][i_ * 2048 + wv * 512]);  \
        }                                                                                    \
    } while (0)

    QKV_STAGE(0, 0);
    int cur = 0;
    for (int k0 = 0; k0 < K; k0 += 64) {
        __syncthreads();                       // buf[cur] landed; prev readers of buf[cur^1] done
        if (k0 + 64 < K) QKV_STAGE(cur ^ 1, k0 + 64);
#pragma unroll
        for (int kk = 0; kk < 2; ++kk) {
            const int rch = ((kk * 4 + qd) ^ (m & 7)) * 8;
            short8 a[4], b[2];
#pragma unroll
            for (int i = 0; i < 4; ++i) a[i] = *(const short8*)&As[cur][(i * 16 + m) * 64 + rch];
#pragma unroll
            for (int j = 0; j < 2; ++j) b[j] = *(const short8*)&Bs[cur][(wv * 32 + j * 16 + m) * 64 + rch];
#pragma unroll
            for (int i = 0; i < 4; ++i)
#pragma unroll
                for (int j = 0; j < 2; ++j)
                    acc[i][j] = __builtin_amdgcn_mfma_f32_16x16x32_bf16(a[i], b[j], acc[i][j], 0, 0, 0);
        }
        cur ^= 1;
    }
#undef QKV_STAGE

    const int by = blockIdx.y;
    if (by < 20) {
        // rope path (q: by<16, k: 16..19); pairs are adjacent cols -> shfl_xor(val,1)
        const float sgn = (m & 1) ? 1.f : -1.f;
        const float qscale = 0.08838834764831845f;   // 1/sqrt(128)
#pragma unroll
        for (int i = 0; i < 4; ++i) {
#pragma unroll
            for (int r = 0; r < 4; ++r) {
                const int t = blockIdx.x * 64 + i * 16 + qd * 4 + r;
                const float* ct = cosT + t * 64;
                const float* st = sinT + t * 64;
#pragma unroll
                for (int j = 0; j < 2; ++j) {
                    const int cq = wv * 32 + j * 16 + m;
                    const int j2 = cq >> 1;
                    float val = acc[i][j][r];
                    float prt = __shfl_xor(val, 1);
                    float o = val * ct[j2] + sgn * prt * st[j2];
                    const int col = by * 128 + cq;
                    if (by < 16) qb[(long)t * Q_SIZE + col] = f2bf(o * qscale);
                    else         kb[(long)t * KV_SIZE + (col - 2048)] = f2bf(o);
                }
            }
        }
    } else {
        // v path: write V^T directly: vt[g][d][t]
        const int g = by - 20;
#pragma unroll
        for (int i = 0; i < 4; ++i)
#pragma unroll
            for (int j = 0; j < 2; ++j) {
                const int d = wv * 32 + j * 16 + m;
                const int t0 = blockIdx.x * 64 + i * 16 + qd * 4;
                unsigned short o4[4];
#pragma unroll
                for (int r = 0; r < 4; ++r) o4[r] = f2bf(acc[i][j][r]);
                *(short4v*)&vt[((long)g * HD + d) * T + t0] = *(short4v*)o4;
            }
    }
}

// ---------------- out GEMM v2 (kept, measured >= v0): 128x128 tile, 4 waves of 64x64 ------------
__global__ __launch_bounds__(256) void gemm_out(const unsigned short* __restrict__ A,
                                                const unsigned short* __restrict__ B,
                                                float* __restrict__ C,
                                                int K, int ldc) {
    __shared__ __align__(16) unsigned short Ls[3][256 * 64];   // 3 x 32 KB
    const int tid = threadIdx.x;
    const int wv = tid >> 6;
    const int lane = tid & 63;
    const int l31 = lane & 31;
    const int hi = lane >> 5;
    const int wr = wv >> 1, wc = wv & 1;
    const int by = blockIdx.x;   // N tile
    const int bx = blockIdx.y;   // M tile
    const unsigned short* Ab = A + (long)(bx * 128) * K;
    const unsigned short* Bb = B + (long)(by * 128) * K;

    floatx16 acc[2][2];
#pragma unroll
    for (int i = 0; i < 2; ++i)
#pragma unroll
        for (int j = 0; j < 2; ++j) acc[i][j] = (floatx16)0.0f;

    // 32 wave-loads per stage, 8 per wave (uniform -> vmcnt(8))
#define OUT_STAGE(bufidx, k0)                                                          \
    do {                                                                               \
        unsigned short* lb_ = &Ls[bufidx][0];                                          \
        _Pragma("unroll") for (int qq_ = 0; qq_ < 8; ++qq_) {                          \
            int q_ = qq_ * 4 + wv;                                                     \
            int s_ = q_ * 64 + lane;                                                   \
            int r_ = s_ >> 3;                                                          \
            int c_ = (s_ & 7) ^ (r_ & 7);                                              \
            const unsigned short* src_ = (q_ < 16)                                     \
                ? (Ab + (long)r_ * K + (k0) + c_ * 8)                                  \
                : (Bb + (long)(r_ - 128) * K + (k0) + c_ * 8);                         \
            gload_lds16(src_, lb_ + q_ * 512);                                         \
        }                                                                              \
    } while (0)

    const int NT = K >> 6;
    OUT_STAGE(0, 0);
    OUT_STAGE(1, 64);
    int cur = 0;
    const int arow0 = wr * 64 + l31;
    const int brow0 = 128 + wc * 64 + l31;
#pragma unroll 1
    for (int t = 0; t < NT; ++t) {
        if (t < NT - 1) VMCNT(8); else VMCNT(0);
        BARRIER_RAW();
        if (t + 2 < NT) {
            int nb = cur + 2; if (nb >= 3) nb -= 3;
            OUT_STAGE(nb, (t + 2) * 64);
        }
        const unsigned short* lb = &Ls[cur][0];
#pragma unroll
        for (int kk = 0; kk < 4; ++kk) {
            const int ck = kk * 2 + hi;
            short8 a[2], b[2];
#pragma unroll
            for (int i = 0; i < 2; ++i) {
                const int row = arow0 + i * 32;
                a[i] = *(const short8*)&lb[row * 64 + ((ck ^ (row & 7)) << 3)];
            }
#pragma unroll
            for (int j = 0; j < 2; ++j) {
                const int row = brow0 + j * 32;
                b[j] = *(const short8*)&lb[row * 64 + ((ck ^ (row & 7)) << 3)];
            }
#pragma unroll
            for (int i = 0; i < 2; ++i)
#pragma unroll
                for (int j = 0; j < 2; ++j)
                    acc[i][j] = __builtin_amdgcn_mfma_f32_32x32x16_bf16(a[i], b[j], acc[i][j], 0, 0, 0);
        }
        LGKMCNT0;
        cur = (cur == 2) ? 0 : cur + 1;
    }
#undef OUT_STAGE

#pragma unroll
    for (int i = 0; i < 2; ++i)
#pragma unroll
        for (int j = 0; j < 2; ++j) {
            const long rbase = (long)(bx * 128 + wr * 64 + i * 32 + 4 * hi);
            const int cbase = by * 128 + wc * 64 + j * 32 + l31;
#pragma unroll
            for (int h = 0; h < 4; ++h)
#pragma unroll
                for (int r = 0; r < 4; ++r)
                    C[(rbase + 8 * h + r) * ldc + cbase] = acc[i][j][h * 4 + r];
        }
}

// ---------------- flash attention v13: v10 structure + in-kernel split-k combine ----------------
// 512 blocks, v10's balanced mapping (heavy qt 15..8 blocks 0..255, light qt 0..7 blocks
// 256..511; CU pair = 17 tiles). After storing partials, last half per unit (atomic flag)
// combines both halves and writes ab directly -> attn_combine kernel eliminated.
__global__ __launch_bounds__(256, 2) void flash_attn(const unsigned short* __restrict__ qb,
                                                     const unsigned short* __restrict__ kb,
                                                     const unsigned short* __restrict__ vt,
                                                     unsigned short* __restrict__ ab,
                                                     float* __restrict__ Opart,
                                                     float* __restrict__ MLpart,
                                                     int* __restrict__ flags) {
    __shared__ __align__(16) unsigned short Kbuf[2][64 * 128];   // 32 KB
    __shared__ __align__(16) unsigned short Vbuf[128 * 64];      // 16 KB
    __shared__ __align__(16) unsigned short Pls[4][32 * 72];     // 18.4 KB

    const int tid = threadIdx.x;
    const int wv = tid >> 6;
    const int lane = tid & 63;
    const int m = lane & 15;
    const int qd = lane >> 4;

    const int bx = blockIdx.x;
    const int c_ = bx & 255;
    const int hi = bx >> 8;
    const int h = c_ >> 4;
    const int j_ = c_ & 15;
    const int qt = hi ? (j_ >> 1) : (15 - (j_ >> 1));
    const int half = j_ & 1;
    const int g = h >> 2;
    unsigned short* myP = Pls[wv];

    const int n0 = qt + 1;
    const int jt0 = half ? n0 : 0;
    const int jt1 = half ? 2 * qt + 2 : n0;
    const int q0 = qt * 128;

    short8 aq[2][4];
#pragma unroll
    for (int s = 0; s < 2; ++s)
#pragma unroll
        for (int kk = 0; kk < 4; ++kk)
            aq[s][kk] = *(const short8*)(qb + (long)(q0 + s * 64 + wv * 16 + m) * Q_SIZE +
                                         h * HD + kk * 32 + qd * 8);

    floatx4 acc_o[2][8];
#pragma unroll
    for (int s = 0; s < 2; ++s)
#pragma unroll
        for (int nb = 0; nb < 8; ++nb) acc_o[s][nb] = (floatx4){0.f, 0.f, 0.f, 0.f};
    float mrow[2] = {-1e30f, -1e30f};
    float lrow[2] = {0.f, 0.f};

    // stage first K tile (XOR chunk swizzle c^(r&15))
#pragma unroll
    for (int i = 0; i < 4; ++i) {
        int s_ = i * 256 + tid;
        int r = s_ >> 4, c = (s_ & 15) ^ (r & 15);
        gload_lds16(kb + (long)(jt0 * 64 + r) * KV_SIZE + g * HD + c * 8,
                    &Kbuf[0][i * 2048 + wv * 512]);
    }
    int cur = 0;
    for (int jt = jt0; jt < jt1; ++jt) {
        VMCNT(0);          // K[cur] landed (issued a full tile ago)
        BARRIER_RAW();

        // V for CURRENT tile FIRST (must be older than the K prefetch for vmcnt(4))
#pragma unroll
        for (int i = 0; i < 4; ++i) {
            int s_ = i * 256 + tid;
            int r = s_ >> 3, c = (s_ & 7) ^ (r & 7);
            gload_lds16(vt + ((long)g * HD + r) * T + jt * 64 + c * 8,
                        &Vbuf[i * 2048 + wv * 512]);
        }
        const bool pk = (jt + 1 < jt1);
        if (pk) {   // K prefetch -> other buffer (stays in flight through PV)
#pragma unroll
            for (int i = 0; i < 4; ++i) {
                int s_ = i * 256 + tid;
                int r = s_ >> 4, c = (s_ & 15) ^ (r & 15);
                gload_lds16(kb + (long)((jt + 1) * 64 + r) * KV_SIZE + g * HD + c * 8,
                            &Kbuf[cur ^ 1][i * 2048 + wv * 512]);
            }
        }

        // S^T = K Q^T for both q-sets, sharing K fragment loads
        floatx4 acc_s[2][4];
#pragma unroll
        for (int s = 0; s < 2; ++s)
#pragma unroll
            for (int c = 0; c < 4; ++c) acc_s[s][c] = (floatx4){0.f, 0.f, 0.f, 0.f};
#pragma unroll
        for (int kk = 0; kk < 4; ++kk) {
#pragma unroll
            for (int c = 0; c < 4; ++c) {
                short8 ak = *(const short8*)&Kbuf[cur][(c * 16 + m) * 128 +
                                                       (((4 * kk + qd) ^ m) * 8)];
                acc_s[0][c] = __builtin_amdgcn_mfma_f32_16x16x32_bf16(ak, aq[0][kk], acc_s[0][c], 0, 0, 0);
                acc_s[1][c] = __builtin_amdgcn_mfma_f32_16x16x32_bf16(ak, aq[1][kk], acc_s[1][c], 0, 0, 0);
            }
        }

        // per-set online softmax + P write
#pragma unroll
        for (int s = 0; s < 2; ++s) {
            const int dg = 2 * qt + s;
            if (jt >= dg) {
                const bool full = (jt > dg);
#pragma unroll
                for (int c = 0; c < 4; ++c)
#pragma unroll
                    for (int r = 0; r < 4; ++r)
                        if (full || (c * 16 + qd * 4 + r > wv * 16 + m)) acc_s[s][c][r] = -1e30f;
            }
            float mx = acc_s[s][0][0];
#pragma unroll
            for (int c = 0; c < 4; ++c)
#pragma unroll
                for (int r = 0; r < 4; ++r) mx = fmaxf(mx, acc_s[s][c][r]);
            mx = fmaxf(mx, __shfl_xor(mx, 16));
            mx = fmaxf(mx, __shfl_xor(mx, 32));
            float mnew = fmaxf(mrow[s], mx);
            float alpha = __expf(mrow[s] - mnew);
            mrow[s] = mnew;

            float pv[4][4];
            float lsum = 0.f;
#pragma unroll
            for (int c = 0; c < 4; ++c)
#pragma unroll
                for (int r = 0; r < 4; ++r) {
                    pv[c][r] = __expf(acc_s[s][c][r] - mnew);
                    lsum += pv[c][r];
                }
            lsum += __shfl_xor(lsum, 16);
            lsum += __shfl_xor(lsum, 32);
            lrow[s] = lrow[s] * alpha + lsum;
#pragma unroll
            for (int nb = 0; nb < 8; ++nb)
#pragma unroll
                for (int r = 0; r < 4; ++r) acc_o[s][nb][r] *= alpha;
#pragma unroll
            for (int c = 0; c < 4; ++c) {
                short4v pk2 = {(short)f2bf(pv[c][0]), (short)f2bf(pv[c][1]),
                               (short)f2bf(pv[c][2]), (short)f2bf(pv[c][3])};
                *(short4v*)&myP[(s * 16 + m) * 72 + c * 16 + qd * 4] = pk2;
            }
        }

        if (pk) VMCNT(4); else VMCNT(0);   // force V, keep K(t+1) in flight
        BARRIER_RAW();

        // PV for both sets, sharing V fragment loads
#pragma unroll
        for (int kk = 0; kk < 2; ++kk) {
            short8 pa0 = *(const short8*)&myP[m * 72 + kk * 32 + qd * 8];
            short8 pa1 = *(const short8*)&myP[(16 + m) * 72 + kk * 32 + qd * 8];
#pragma unroll
            for (int nb = 0; nb < 8; ++nb) {
                short8 av = *(const short8*)&Vbuf[(nb * 16 + m) * 64 +
                                                  (((4 * kk + qd) ^ (m & 7)) * 8)];
                acc_o[0][nb] = __builtin_amdgcn_mfma_f32_16x16x32_bf16(av, pa0, acc_o[0][nb], 0, 0, 0);
                acc_o[1][nb] = __builtin_amdgcn_mfma_f32_16x16x32_bf16(av, pa1, acc_o[1][nb], 0, 0, 0);
            }
        }
        LGKMCNT0;   // my LDS reads retired before the next top barrier
        cur ^= 1;
    }

    // store partials for this half
    const int u2 = h * 16 + qt;
    const int unit = u2 * 2 + half;
#pragma unroll
    for (int s = 0; s < 2; ++s) {
        const long rb = (long)unit * 128 + s * 64 + wv * 16 + m;
#pragma unroll
        for (int nb = 0; nb < 8; ++nb)
            *(floatx4*)&Opart[rb * 128 + nb * 16 + qd * 4] = acc_o[s][nb];
        if (qd == 0) {
            MLpart[rb * 2]     = mrow[s];
            MLpart[rb * 2 + 1] = lrow[s];
        }
    }

    // split-k handshake: last half per unit combines both and writes ab
    __syncthreads();                       // all partial stores complete (vmcnt drained)
    __shared__ int amLastSh;
    if (tid == 0) {
        __threadfence();                   // release: partials visible device-wide
        amLastSh = (atomicAdd(&flags[u2], 1) == 1);
    }
    __syncthreads();
    if (amLastSh) {
        __threadfence();                   // acquire: invalidate stale lines before reading
        const int row = tid >> 1;          // 0..127
        const int c0 = (tid & 1) * 64;     // two threads per row
        const long r0 = (long)(u2 * 2) * 128 + row;
        const long r1 = r0 + 128;
        float m0 = MLpart[r0 * 2], l0 = MLpart[r0 * 2 + 1];
        float m1 = MLpart[r1 * 2], l1 = MLpart[r1 * 2 + 1];
        float M = fmaxf(m0, m1);
        float a0 = __expf(m0 - M), a1 = __expf(m1 - M);
        float inv = 1.f / (l0 * a0 + l1 * a1);
        const float* O0 = Opart + r0 * 128 + c0;
        const float* O1 = Opart + r1 * 128 + c0;
        unsigned short* dst = ab + (long)(q0 + row) * Q_SIZE + h * HD + c0;
#pragma unroll
        for (int j = 0; j < 64; j += 4) {
            float4 x0 = *(const float4*)(O0 + j);
            float4 x1 = *(const float4*)(O1 + j);
            unsigned short ov[4];
            ov[0] = f2bf((x0.x * a0 + x1.x * a1) * inv);
            ov[1] = f2bf((x0.y * a0 + x1.y * a1) * inv);
            ov[2] = f2bf((x0.z * a0 + x1.z * a1) * inv);
            ov[3] = f2bf((x0.w * a0 + x1.w * a1) * inv);
            *(short4v*)(dst + j) = *(short4v*)ov;
        }
    }
}

extern "C" void kernel_launch(void* const* d_in, const int* in_sizes, int n_in,
                              void* d_out, int out_size, void* d_ws, size_t ws_size,
                              hipStream_t stream) {
    const int* positions = (const int*)d_in[0];
    const float* hidden  = (const float*)d_in[1];
    const float* w_qkv   = (const float*)d_in[2];
    const float* w_o     = (const float*)d_in[3];
    float* out = (float*)d_out;

    char* p = (char*)d_ws;
    auto alloc = [&](size_t bytes) { char* r = p; p += (bytes + 255) & ~(size_t)255; return r; };
    float* cosT = (float*)alloc((size_t)T * 64 * 4);
    float* sinT = (float*)alloc((size_t)T * 64 * 4);
    unsigned short* hb  = (unsigned short*)alloc((size_t)T * HIDDEN * 2);
    unsigned short* wqt = (unsigned short*)alloc((size_t)QKV_N * HIDDEN * 2);
    unsigned short* wot = (unsigned short*)alloc((size_t)HIDDEN * HIDDEN * 2);
    unsigned short* qb  = (unsigned short*)alloc((size_t)T * Q_SIZE * 2);
    unsigned short* kb  = (unsigned short*)alloc((size_t)T * KV_SIZE * 2);
    unsigned short* vt  = (unsigned short*)alloc((size_t)T * KV_SIZE * 2);
    unsigned short* ab  = (unsigned short*)alloc((size_t)T * Q_SIZE * 2);
    float* Opart  = (float*)alloc((size_t)512 * 128 * 128 * 4);   // 33.5 MB
    float* MLpart = (float*)alloc((size_t)512 * 128 * 2 * 4);
    int*   flags  = (int*)alloc(256 * 4);

    // 1) fused prep (convert + 2 transposes + cos/sin tables)
    prep_misc<<<dim3(14848), 256, 0, stream>>>(hidden, w_qkv, w_o, positions,
                                               hb, wqt, wot, cosT, sinT);
    // 2) fused qkv projection + rope (also zeroes fa flags)
    gemm_qkv<<<dim3(T / 64, QKV_N / 128), 256, 0, stream>>>(hb, wqt, cosT, sinT, qb, kb, vt, flags);
    // 3) fused causal attention, 512 balanced blocks, in-kernel split-k combine
    flash_attn<<<dim3(512), 256, 0, stream>>>(qb, kb, vt, ab, Opart, MLpart, flags);
    // 4) out = attn @ w_o (gout_v2)
    gemm_out<<<dim3(HIDDEN / 128, T / 128), 256, 0, stream>>>(ab, wot, out, Q_SIZE, HIDDEN);
}

// Round 9
// 212.527 us; speedup vs baseline: 1.3744x; 1.3744x over previous
//
#include <hip/hip_runtime.h>
#include <math.h>

#define T 2048
#define HIDDEN 2048
#define NH 16
#define NKV 4
#define HD 128
#define QKV_N 3072   // (16 + 2*4) * 128
#define Q_SIZE 2048  // 16*128
#define KV_SIZE 512  // 4*128

typedef __attribute__((ext_vector_type(8))) short short8;
typedef __attribute__((ext_vector_type(4))) short short4v;
typedef __attribute__((ext_vector_type(4))) float floatx4;
typedef __attribute__((ext_vector_type(16))) float floatx16;

// counted-waitcnt plumbing: memory-clobber asm fences prevent the compiler from
// moving loads/gload_lds across the wait+barrier pair
#define VMCNT(N) asm volatile("s_waitcnt vmcnt(" #N ")" ::: "memory")
#define LGKMCNT0 asm volatile("s_waitcnt lgkmcnt(0)" ::: "memory")
#define BARRIER_RAW()                          \
    do {                                       \
        __builtin_amdgcn_s_barrier();          \
        asm volatile("" ::: "memory");         \
    } while (0)

__device__ __forceinline__ unsigned short f2bf(float f) {
    union { float f; unsigned int u; } v; v.f = f;
    unsigned int u = v.u;
    u += 0x7fffu + ((u >> 16) & 1u);   // round-to-nearest-even
    return (unsigned short)(u >> 16);
}

// async global->LDS, 16B per lane; LDS dest = wave-uniform base + lane*16 (HW adds it)
__device__ __forceinline__ void gload_lds16(const unsigned short* g, unsigned short* l) {
    __builtin_amdgcn_global_load_lds((const __attribute__((address_space(1))) unsigned int*)g,
                                     (__attribute__((address_space(3))) unsigned int*)l, 16, 0, 0);
}

// ---------------- fused prep: convert hb + transpose wqt + transpose wot + cos/sin ----------------
__global__ __launch_bounds__(256) void prep_misc(const float* __restrict__ hidden,
                                                 const float* __restrict__ w_qkv,
                                                 const float* __restrict__ w_o,
                                                 const int* __restrict__ positions,
                                                 unsigned short* __restrict__ hb,
                                                 unsigned short* __restrict__ wqt,
                                                 unsigned short* __restrict__ wot,
                                                 float* __restrict__ cosT,
                                                 float* __restrict__ sinT) {
    __shared__ float tile[32][33];
    const int b = blockIdx.x;
    const int tid = threadIdx.x;
    const int tx = tid & 31, ty = tid >> 5;

    if (b < 4096) {
        int i = (b * 256 + tid) * 4;
        float4 v = *(const float4*)(hidden + i);
        hb[i]     = f2bf(v.x);
        hb[i + 1] = f2bf(v.y);
        hb[i + 2] = f2bf(v.z);
        hb[i + 3] = f2bf(v.w);
    } else if (b < 10240) {
        int idx = b - 4096;
        int c0 = (idx % 96) * 32, r0 = (idx / 96) * 32;
#pragma unroll
        for (int i = 0; i < 4; ++i)
            tile[ty + i * 8][tx] = w_qkv[(long)(r0 + ty + i * 8) * QKV_N + c0 + tx];
        __syncthreads();
#pragma unroll
        for (int i = 0; i < 4; ++i)
            wqt[(long)(c0 + ty + i * 8) * HIDDEN + r0 + tx] = f2bf(tile[tx][ty + i * 8]);
    } else if (b < 14336) {
        int idx = b - 10240;
        int c0 = (idx % 64) * 32, r0 = (idx / 64) * 32;
#pragma unroll
        for (int i = 0; i < 4; ++i)
            tile[ty + i * 8][tx] = w_o[(long)(r0 + ty + i * 8) * HIDDEN + c0 + tx];
        __syncthreads();
#pragma unroll
        for (int i = 0; i < 4; ++i)
            wot[(long)(c0 + ty + i * 8) * HIDDEN + r0 + tx] = f2bf(tile[tx][ty + i * 8]);
    } else {
        int idx = b - 14336;
        int t = idx * 4 + (tid >> 6);
        int j = tid & 63;
        int row = (j >= 44) ? 0 : ((j & 1) ? 2 : 1);
        int pos = positions[row * T + t];
        float invf = exp2f((float)j * -0.29580571f);   // log2(500000)/64
        float ang = (float)pos * invf;
        cosT[t * 64 + j] = cosf(ang);
        sinT[t * 64 + j] = sinf(ang);
    }
}

// ---------------- qkv GEMM (v0, measured 45.4us): 64x128 tile, BK=64, dbuf async, rope fused ----
__global__ __launch_bounds__(256) void gemm_qkv(const unsigned short* __restrict__ A,
                                                const unsigned short* __restrict__ B,
                                                const float* __restrict__ cosT,
                                                const float* __restrict__ sinT,
                                                unsigned short* __restrict__ qb,
                                                unsigned short* __restrict__ kb,
                                                unsigned short* __restrict__ vt) {
    __shared__ __align__(16) unsigned short As[2][64 * 64];    // 2 x 8 KB
    __shared__ __align__(16) unsigned short Bs[2][128 * 64];   // 2 x 16 KB
    const int K = HIDDEN;
    const int tid = threadIdx.x;
    const int wv = tid >> 6;
    const int lane = tid & 63;
    const int m = lane & 15, qd = lane >> 4;
    const unsigned short* Ab = A + (long)(blockIdx.x * 64) * K;
    const unsigned short* Bb = B + (long)(blockIdx.y * 128) * K;

    floatx4 acc[4][2];
#pragma unroll
    for (int i = 0; i < 4; ++i)
#pragma unroll
        for (int j = 0; j < 2; ++j) acc[i][j] = (floatx4){0.f, 0.f, 0.f, 0.f};

#define QKV_STAGE(buf, k0)                                                                   \
    do {                                                                                     \
        _Pragma("unroll") for (int i_ = 0; i_ < 2; ++i_) {                                   \
            int s_ = i_ * 256 + tid, r_ = s_ >> 3, c_ = (s_ & 7) ^ (r_ & 7);                 \
            gload_lds16(Ab + (long)r_ * K + (k0) + c_ * 8, &As[buf][i_ * 2048 + wv * 512]);  \
        }                                                                                    \
        _Pragma("unroll") for (int i_ = 0; i_ < 4; ++i_) {                                   \
            int s_ = i_ * 256 + tid, r_ = s_ >> 3, c_ = (s_ & 7) ^ (r_ & 7);                 \
            gload_lds16(Bb + (long)r_ * K + (k0) + c_ * 8, &Bs[buf][i_ * 2048 + wv * 512]);  \
        }                                                                                    \
    } while (0)

    QKV_STAGE(0, 0);
    int cur = 0;
    for (int k0 = 0; k0 < K; k0 += 64) {
        __syncthreads();                       // buf[cur] landed; prev readers of buf[cur^1] done
        if (k0 + 64 < K) QKV_STAGE(cur ^ 1, k0 + 64);
#pragma unroll
        for (int kk = 0; kk < 2; ++kk) {
            const int rch = ((kk * 4 + qd) ^ (m & 7)) * 8;
            short8 a[4], b[2];
#pragma unroll
            for (int i = 0; i < 4; ++i) a[i] = *(const short8*)&As[cur][(i * 16 + m) * 64 + rch];
#pragma unroll
            for (int j = 0; j < 2; ++j) b[j] = *(const short8*)&Bs[cur][(wv * 32 + j * 16 + m) * 64 + rch];
#pragma unroll
            for (int i = 0; i < 4; ++i)
#pragma unroll
                for (int j = 0; j < 2; ++j)
                    acc[i][j] = __builtin_amdgcn_mfma_f32_16x16x32_bf16(a[i], b[j], acc[i][j], 0, 0, 0);
        }
        cur ^= 1;
    }
#undef QKV_STAGE

    const int by = blockIdx.y;
    if (by < 20) {
        // rope path (q: by<16, k: 16..19); pairs are adjacent cols -> shfl_xor(val,1)
        const float sgn = (m & 1) ? 1.f : -1.f;
        const float qscale = 0.08838834764831845f;   // 1/sqrt(128)
#pragma unroll
        for (int i = 0; i < 4; ++i) {
#pragma unroll
            for (int r = 0; r < 4; ++r) {
                const int t = blockIdx.x * 64 + i * 16 + qd * 4 + r;
                const float* ct = cosT + t * 64;
                const float* st = sinT + t * 64;
#pragma unroll
                for (int j = 0; j < 2; ++j) {
                    const int cq = wv * 32 + j * 16 + m;
                    const int j2 = cq >> 1;
                    float val = acc[i][j][r];
                    float prt = __shfl_xor(val, 1);
                    float o = val * ct[j2] + sgn * prt * st[j2];
                    const int col = by * 128 + cq;
                    if (by < 16) qb[(long)t * Q_SIZE + col] = f2bf(o * qscale);
                    else         kb[(long)t * KV_SIZE + (col - 2048)] = f2bf(o);
                }
            }
        }
    } else {
        // v path: write V^T directly: vt[g][d][t]
        const int g = by - 20;
#pragma unroll
        for (int i = 0; i < 4; ++i)
#pragma unroll
            for (int j = 0; j < 2; ++j) {
                const int d = wv * 32 + j * 16 + m;
                const int t0 = blockIdx.x * 64 + i * 16 + qd * 4;
                unsigned short o4[4];
#pragma unroll
                for (int r = 0; r < 4; ++r) o4[r] = f2bf(acc[i][j][r]);
                *(short4v*)&vt[((long)g * HD + d) * T + t0] = *(short4v*)o4;
            }
    }
}

// ---------------- out GEMM v2 (kept): 128x128 tile, 4 waves of 64x64 (32x32x16 MFMA) ------------
__global__ __launch_bounds__(256) void gemm_out(const unsigned short* __restrict__ A,
                                                const unsigned short* __restrict__ B,
                                                float* __restrict__ C,
                                                int K, int ldc) {
    __shared__ __align__(16) unsigned short Ls[3][256 * 64];   // 3 x 32 KB
    const int tid = threadIdx.x;
    const int wv = tid >> 6;
    const int lane = tid & 63;
    const int l31 = lane & 31;
    const int hi = lane >> 5;
    const int wr = wv >> 1, wc = wv & 1;
    const int by = blockIdx.x;   // N tile
    const int bx = blockIdx.y;   // M tile
    const unsigned short* Ab = A + (long)(bx * 128) * K;
    const unsigned short* Bb = B + (long)(by * 128) * K;

    floatx16 acc[2][2];
#pragma unroll
    for (int i = 0; i < 2; ++i)
#pragma unroll
        for (int j = 0; j < 2; ++j) acc[i][j] = (floatx16)0.0f;

    // 32 wave-loads per stage, 8 per wave (uniform -> vmcnt(8))
#define OUT_STAGE(bufidx, k0)                                                          \
    do {                                                                               \
        unsigned short* lb_ = &Ls[bufidx][0];                                          \
        _Pragma("unroll") for (int qq_ = 0; qq_ < 8; ++qq_) {                          \
            int q_ = qq_ * 4 + wv;                                                     \
            int s_ = q_ * 64 + lane;                                                   \
            int r_ = s_ >> 3;                                                          \
            int c_ = (s_ & 7) ^ (r_ & 7);                                              \
            const unsigned short* src_ = (q_ < 16)                                     \
                ? (Ab + (long)r_ * K + (k0) + c_ * 8)                                  \
                : (Bb + (long)(r_ - 128) * K + (k0) + c_ * 8);                         \
            gload_lds16(src_, lb_ + q_ * 512);                                         \
        }                                                                              \
    } while (0)

    const int NT = K >> 6;
    OUT_STAGE(0, 0);
    OUT_STAGE(1, 64);
    int cur = 0;
    const int arow0 = wr * 64 + l31;
    const int brow0 = 128 + wc * 64 + l31;
#pragma unroll 1
    for (int t = 0; t < NT; ++t) {
        if (t < NT - 1) VMCNT(8); else VMCNT(0);
        BARRIER_RAW();
        if (t + 2 < NT) {
            int nb = cur + 2; if (nb >= 3) nb -= 3;
            OUT_STAGE(nb, (t + 2) * 64);
        }
        const unsigned short* lb = &Ls[cur][0];
#pragma unroll
        for (int kk = 0; kk < 4; ++kk) {
            const int ck = kk * 2 + hi;
            short8 a[2], b[2];
#pragma unroll
            for (int i = 0; i < 2; ++i) {
                const int row = arow0 + i * 32;
                a[i] = *(const short8*)&lb[row * 64 + ((ck ^ (row & 7)) << 3)];
            }
#pragma unroll
            for (int j = 0; j < 2; ++j) {
                const int row = brow0 + j * 32;
                b[j] = *(const short8*)&lb[row * 64 + ((ck ^ (row & 7)) << 3)];
            }
#pragma unroll
            for (int i = 0; i < 2; ++i)
#pragma unroll
                for (int j = 0; j < 2; ++j)
                    acc[i][j] = __builtin_amdgcn_mfma_f32_32x32x16_bf16(a[i], b[j], acc[i][j], 0, 0, 0);
        }
        LGKMCNT0;
        cur = (cur == 2) ? 0 : cur + 1;
    }
#undef OUT_STAGE

#pragma unroll
    for (int i = 0; i < 2; ++i)
#pragma unroll
        for (int j = 0; j < 2; ++j) {
            const long rbase = (long)(bx * 128 + wr * 64 + i * 32 + 4 * hi);
            const int cbase = by * 128 + wc * 64 + j * 32 + l31;
#pragma unroll
            for (int h = 0; h < 4; ++h)
#pragma unroll
                for (int r = 0; r < 4; ++r)
                    C[(rbase + 8 * h + r) * ldc + cbase] = acc[i][j][h * 4 + r];
        }
}

// ---------------- flash attention v10 (measured best): counted-vmcnt barriers ----------------
__global__ __launch_bounds__(256, 2) void flash_attn(const unsigned short* __restrict__ qb,
                                                     const unsigned short* __restrict__ kb,
                                                     const unsigned short* __restrict__ vt,
                                                     float* __restrict__ Opart,
                                                     float* __restrict__ MLpart) {
    __shared__ __align__(16) unsigned short Kbuf[2][64 * 128];   // 32 KB
    __shared__ __align__(16) unsigned short Vbuf[128 * 64];      // 16 KB
    __shared__ __align__(16) unsigned short Pls[4][32 * 72];     // 18.4 KB

    const int tid = threadIdx.x;
    const int wv = tid >> 6;
    const int lane = tid & 63;
    const int m = lane & 15;
    const int qd = lane >> 4;

    const int bx = blockIdx.x;
    const int c_ = bx & 255;
    const int hi = bx >> 8;
    const int h = c_ >> 4;
    const int j_ = c_ & 15;
    const int qt = hi ? (j_ >> 1) : (15 - (j_ >> 1));
    const int half = j_ & 1;
    const int g = h >> 2;
    unsigned short* myP = Pls[wv];

    const int n0 = qt + 1;
    const int jt0 = half ? n0 : 0;
    const int jt1 = half ? 2 * qt + 2 : n0;
    const int q0 = qt * 128;

    short8 aq[2][4];
#pragma unroll
    for (int s = 0; s < 2; ++s)
#pragma unroll
        for (int kk = 0; kk < 4; ++kk)
            aq[s][kk] = *(const short8*)(qb + (long)(q0 + s * 64 + wv * 16 + m) * Q_SIZE +
                                         h * HD + kk * 32 + qd * 8);

    floatx4 acc_o[2][8];
#pragma unroll
    for (int s = 0; s < 2; ++s)
#pragma unroll
        for (int nb = 0; nb < 8; ++nb) acc_o[s][nb] = (floatx4){0.f, 0.f, 0.f, 0.f};
    float mrow[2] = {-1e30f, -1e30f};
    float lrow[2] = {0.f, 0.f};

    // stage first K tile (XOR chunk swizzle c^(r&15))
#pragma unroll
    for (int i = 0; i < 4; ++i) {
        int s_ = i * 256 + tid;
        int r = s_ >> 4, c = (s_ & 15) ^ (r & 15);
        gload_lds16(kb + (long)(jt0 * 64 + r) * KV_SIZE + g * HD + c * 8,
                    &Kbuf[0][i * 2048 + wv * 512]);
    }
    int cur = 0;
    for (int jt = jt0; jt < jt1; ++jt) {
        VMCNT(0);          // K[cur] landed (issued a full tile ago)
        BARRIER_RAW();

        // V for CURRENT tile FIRST (must be older than the K prefetch for vmcnt(4))
#pragma unroll
        for (int i = 0; i < 4; ++i) {
            int s_ = i * 256 + tid;
            int r = s_ >> 3, c = (s_ & 7) ^ (r & 7);
            gload_lds16(vt + ((long)g * HD + r) * T + jt * 64 + c * 8,
                        &Vbuf[i * 2048 + wv * 512]);
        }
        const bool pk = (jt + 1 < jt1);
        if (pk) {   // K prefetch -> other buffer (stays in flight through PV)
#pragma unroll
            for (int i = 0; i < 4; ++i) {
                int s_ = i * 256 + tid;
                int r = s_ >> 4, c = (s_ & 15) ^ (r & 15);
                gload_lds16(kb + (long)((jt + 1) * 64 + r) * KV_SIZE + g * HD + c * 8,
                            &Kbuf[cur ^ 1][i * 2048 + wv * 512]);
            }
        }

        // S^T = K Q^T for both q-sets, sharing K fragment loads
        floatx4 acc_s[2][4];
#pragma unroll
        for (int s = 0; s < 2; ++s)
#pragma unroll
            for (int c = 0; c < 4; ++c) acc_s[s][c] = (floatx4){0.f, 0.f, 0.f, 0.f};
#pragma unroll
        for (int kk = 0; kk < 4; ++kk) {
#pragma unroll
            for (int c = 0; c < 4; ++c) {
                short8 ak = *(const short8*)&Kbuf[cur][(c * 16 + m) * 128 +
                                                       (((4 * kk + qd) ^ m) * 8)];
                acc_s[0][c] = __builtin_amdgcn_mfma_f32_16x16x32_bf16(ak, aq[0][kk], acc_s[0][c], 0, 0, 0);
                acc_s[1][c] = __builtin_amdgcn_mfma_f32_16x16x32_bf16(ak, aq[1][kk], acc_s[1][c], 0, 0, 0);
            }
        }

        // per-set online softmax + P write
#pragma unroll
        for (int s = 0; s < 2; ++s) {
            const int dg = 2 * qt + s;
            if (jt >= dg) {
                const bool full = (jt > dg);
#pragma unroll
                for (int c = 0; c < 4; ++c)
#pragma unroll
                    for (int r = 0; r < 4; ++r)
                        if (full || (c * 16 + qd * 4 + r > wv * 16 + m)) acc_s[s][c][r] = -1e30f;
            }
            float mx = acc_s[s][0][0];
#pragma unroll
            for (int c = 0; c < 4; ++c)
#pragma unroll
                for (int r = 0; r < 4; ++r) mx = fmaxf(mx, acc_s[s][c][r]);
            mx = fmaxf(mx, __shfl_xor(mx, 16));
            mx = fmaxf(mx, __shfl_xor(mx, 32));
            float mnew = fmaxf(mrow[s], mx);
            float alpha = __expf(mrow[s] - mnew);
            mrow[s] = mnew;

            float pv[4][4];
            float lsum = 0.f;
#pragma unroll
            for (int c = 0; c < 4; ++c)
#pragma unroll
                for (int r = 0; r < 4; ++r) {
                    pv[c][r] = __expf(acc_s[s][c][r] - mnew);
                    lsum += pv[c][r];
                }
            lsum += __shfl_xor(lsum, 16);
            lsum += __shfl_xor(lsum, 32);
            lrow[s] = lrow[s] * alpha + lsum;
#pragma unroll
            for (int nb = 0; nb < 8; ++nb)
#pragma unroll
                for (int r = 0; r < 4; ++r) acc_o[s][nb][r] *= alpha;
#pragma unroll
            for (int c = 0; c < 4; ++c) {
                short4v pk2 = {(short)f2bf(pv[c][0]), (short)f2bf(pv[c][1]),
                               (short)f2bf(pv[c][2]), (short)f2bf(pv[c][3])};
                *(short4v*)&myP[(s * 16 + m) * 72 + c * 16 + qd * 4] = pk2;
            }
        }

        if (pk) VMCNT(4); else VMCNT(0);   // force V, keep K(t+1) in flight
        BARRIER_RAW();

        // PV for both sets, sharing V fragment loads
#pragma unroll
        for (int kk = 0; kk < 2; ++kk) {
            short8 pa0 = *(const short8*)&myP[m * 72 + kk * 32 + qd * 8];
            short8 pa1 = *(const short8*)&myP[(16 + m) * 72 + kk * 32 + qd * 8];
#pragma unroll
            for (int nb = 0; nb < 8; ++nb) {
                short8 av = *(const short8*)&Vbuf[(nb * 16 + m) * 64 +
                                                  (((4 * kk + qd) ^ (m & 7)) * 8)];
                acc_o[0][nb] = __builtin_amdgcn_mfma_f32_16x16x32_bf16(av, pa0, acc_o[0][nb], 0, 0, 0);
                acc_o[1][nb] = __builtin_amdgcn_mfma_f32_16x16x32_bf16(av, pa1, acc_o[1][nb], 0, 0, 0);
            }
        }
        LGKMCNT0;   // my LDS reads retired before the next top barrier
        cur ^= 1;
    }

    // store partials for this unit
    const int unit = (h * 16 + qt) * 2 + half;
#pragma unroll
    for (int s = 0; s < 2; ++s) {
        const long rb = (long)unit * 128 + s * 64 + wv * 16 + m;
#pragma unroll
        for (int nb = 0; nb < 8; ++nb)
            *(floatx4*)&Opart[rb * 128 + nb * 16 + qd * 4] = acc_o[s][nb];
        if (qd == 0) {
            MLpart[rb * 2]     = mrow[s];
            MLpart[rb * 2 + 1] = lrow[s];
        }
    }
}

// ---------------- combine K-split partials -> ab bf16 [t][h*128+d] ----------------
__global__ __launch_bounds__(256) void attn_combine(const float* __restrict__ Opart,
                                                    const float* __restrict__ MLpart,
                                                    unsigned short* __restrict__ ab) {
    const int tid = threadIdx.x;
    const int q = blockIdx.x * 16 + (tid >> 4);
    const int h = blockIdx.y;
    const int d0 = (tid & 15) * 8;
    const int qt = q >> 7, lr = q & 127;
    const long r0 = ((long)(h * 16 + qt) * 2) * 128 + lr;
    const long r1 = r0 + 128;
    float m0 = MLpart[r0 * 2], l0 = MLpart[r0 * 2 + 1];
    float m1 = MLpart[r1 * 2], l1 = MLpart[r1 * 2 + 1];
    float M = fmaxf(m0, m1);
    float a0 = __expf(m0 - M), a1 = __expf(m1 - M);
    float inv = 1.f / (l0 * a0 + l1 * a1);
    const float* O0 = Opart + r0 * 128 + d0;
    const float* O1 = Opart + r1 * 128 + d0;
    unsigned short outv[8];
#pragma unroll
    for (int j = 0; j < 8; j += 4) {
        float4 x0 = *(const float4*)(O0 + j);
        float4 x1 = *(const float4*)(O1 + j);
        outv[j]     = f2bf((x0.x * a0 + x1.x * a1) * inv);
        outv[j + 1] = f2bf((x0.y * a0 + x1.y * a1) * inv);
        outv[j + 2] = f2bf((x0.z * a0 + x1.z * a1) * inv);
        outv[j + 3] = f2bf((x0.w * a0 + x1.w * a1) * inv);
    }
    *(short8*)&ab[(long)q * Q_SIZE + h * HD + d0] = *(short8*)outv;
}

extern "C" void kernel_launch(void* const* d_in, const int* in_sizes, int n_in,
                              void* d_out, int out_size, void* d_ws, size_t ws_size,
                              hipStream_t stream) {
    const int* positions = (const int*)d_in[0];
    const float* hidden  = (const float*)d_in[1];
    const float* w_qkv   = (const float*)d_in[2];
    const float* w_o     = (const float*)d_in[3];
    float* out = (float*)d_out;

    char* p = (char*)d_ws;
    auto alloc = [&](size_t bytes) { char* r = p; p += (bytes + 255) & ~(size_t)255; return r; };
    float* cosT = (float*)alloc((size_t)T * 64 * 4);
    float* sinT = (float*)alloc((size_t)T * 64 * 4);
    unsigned short* hb  = (unsigned short*)alloc((size_t)T * HIDDEN * 2);
    unsigned short* wqt = (unsigned short*)alloc((size_t)QKV_N * HIDDEN * 2);
    unsigned short* wot = (unsigned short*)alloc((size_t)HIDDEN * HIDDEN * 2);
    unsigned short* qb  = (unsigned short*)alloc((size_t)T * Q_SIZE * 2);
    unsigned short* kb  = (unsigned short*)alloc((size_t)T * KV_SIZE * 2);
    unsigned short* vt  = (unsigned short*)alloc((size_t)T * KV_SIZE * 2);
    unsigned short* ab  = (unsigned short*)alloc((size_t)T * Q_SIZE * 2);
    float* Opart  = (float*)alloc((size_t)512 * 128 * 128 * 4);   // 33.5 MB
    float* MLpart = (float*)alloc((size_t)512 * 128 * 2 * 4);

    // 1) fused prep (convert + 2 transposes + cos/sin tables)
    prep_misc<<<dim3(14848), 256, 0, stream>>>(hidden, w_qkv, w_o, positions,
                                               hb, wqt, wot, cosT, sinT);
    // 2) fused qkv projection + rope -> qb (scaled), kb, vt (v0 structure, 45.4us known)
    gemm_qkv<<<dim3(T / 64, QKV_N / 128), 256, 0, stream>>>(hb, wqt, cosT, sinT, qb, kb, vt);
    // 3) fused causal attention, 512 balanced blocks (fa_v10, measured best)
    flash_attn<<<dim3(512), 256, 0, stream>>>(qb, kb, vt, Opart, MLpart);
    // 4) combine partials
    attn_combine<<<dim3(T / 16, NH), 256, 0, stream>>>(Opart, MLpart, ab);
    // 5) out = attn @ w_o (gout_v2)
    gemm_out<<<dim3(HIDDEN / 128, T / 128), 256, 0, stream>>>(ab, wot, out, Q_SIZE, HIDDEN);
}